// Round 1
// baseline (49.553 us; speedup 1.0000x reference)
//
#include <hip/hip_runtime.h>
#include <math.h>

#define N_BLOCKS 2048
#define N_THREADS 256

// Sum of (z1+z2+2.6)^2 over a grid-stride range of float4s, one partial per block.
__global__ void __launch_bounds__(N_THREADS)
partial_sumsq_kernel(const float4* __restrict__ z1,
                     const float4* __restrict__ z2,
                     float* __restrict__ partials,
                     int n4) {
    int tid = blockIdx.x * blockDim.x + threadIdx.x;
    int stride = gridDim.x * blockDim.x;

    float acc = 0.0f;
    for (int i = tid; i < n4; i += stride) {
        float4 a = z1[i];
        float4 b = z2[i];
        float t0 = a.x + b.x + 2.6f;
        float t1 = a.y + b.y + 2.6f;
        float t2 = a.z + b.z + 2.6f;
        float t3 = a.w + b.w + 2.6f;
        acc += t0 * t0 + t1 * t1 + t2 * t2 + t3 * t3;
    }

    // wave-64 butterfly reduce
    #pragma unroll
    for (int off = 32; off > 0; off >>= 1)
        acc += __shfl_down(acc, off, 64);

    __shared__ float wave_sums[N_THREADS / 64];
    int lane = threadIdx.x & 63;
    int wave = threadIdx.x >> 6;
    if (lane == 0) wave_sums[wave] = acc;
    __syncthreads();

    if (threadIdx.x == 0) {
        float s = 0.0f;
        #pragma unroll
        for (int w = 0; w < N_THREADS / 64; ++w) s += wave_sums[w];
        partials[blockIdx.x] = s;
    }
}

// Reduce the block partials (double accumulation) and apply scale + constant.
__global__ void __launch_bounds__(N_THREADS)
final_reduce_kernel(const float* __restrict__ partials,
                    int nparts,
                    float* __restrict__ out,
                    double inv_n) {
    double acc = 0.0;
    for (int i = threadIdx.x; i < nparts; i += blockDim.x)
        acc += (double)partials[i];

    #pragma unroll
    for (int off = 32; off > 0; off >>= 1)
        acc += __shfl_down(acc, off, 64);

    __shared__ double wave_sums[N_THREADS / 64];
    int lane = threadIdx.x & 63;
    int wave = threadIdx.x >> 6;
    if (lane == 0) wave_sums[wave] = acc;
    __syncthreads();

    if (threadIdx.x == 0) {
        double s = 0.0;
        #pragma unroll
        for (int w = 0; w < N_THREADS / 64; ++w) s += wave_sums[w];
        // mean(log_likes) = -0.5 * sum(t^2) / N - 0.5*log(2*pi)
        out[0] = (float)(-0.5 * s * inv_n - 0.91893853320467274178);
    }
}

extern "C" void kernel_launch(void* const* d_in, const int* in_sizes, int n_in,
                              void* d_out, int out_size, void* d_ws, size_t ws_size,
                              hipStream_t stream) {
    const float4* z1 = (const float4*)d_in[0];
    const float4* z2 = (const float4*)d_in[1];
    float* out = (float*)d_out;
    float* partials = (float*)d_ws;  // N_BLOCKS floats = 8 KB scratch

    int n = in_sizes[0];       // 33554432 (divisible by 4)
    int n4 = n / 4;

    partial_sumsq_kernel<<<N_BLOCKS, N_THREADS, 0, stream>>>(z1, z2, partials, n4);
    final_reduce_kernel<<<1, N_THREADS, 0, stream>>>(partials, N_BLOCKS, out,
                                                     1.0 / (double)n);
}